// Round 1
// baseline (649.476 us; speedup 1.0000x reference)
//
#include <hip/hip_runtime.h>

#define NTOK 49

typedef __attribute__((ext_vector_type(8))) short short8;
typedef __attribute__((ext_vector_type(4))) float f32x4;
typedef __attribute__((ext_vector_type(4))) unsigned short u16x4;

__device__ __forceinline__ unsigned short f2bf(float f) {
  union { float f; unsigned u; } v; v.f = f;
  unsigned r = v.u + 0x7FFFu + ((v.u >> 16) & 1u);  // round-to-nearest-even
  return (unsigned short)(r >> 16);
}

// ---------------- prep: swizzle weights to bf16 MFMA-fragment order + bias gather ----------------
// w_swz  : [54 ntiles][9 ksteps][64 lanes][8] bf16   (qkv_w, 864x288)
// pw_swz : [3 h][6 nt][3 ks][64 lanes][8]   bf16     (proj_w per-head slices, 96x96)
// bias3  : [3][49][49] f32
__global__ void prep_kernel(const float* __restrict__ qkv_w,
                            const float* __restrict__ proj_w,
                            const float* __restrict__ bias_table,
                            const int* __restrict__ rel_index,
                            unsigned short* __restrict__ w_swz,
                            unsigned short* __restrict__ pw_swz,
                            float* __restrict__ bias3)
{
  int idx = blockIdx.x * 256 + threadIdx.x;
  if (idx < 248832) {
    int f = idx >> 9, r = idx & 511;
    int l = r >> 3, j = r & 7;
    int nt = f / 9, ks = f - nt * 9;
    int row = nt * 16 + (l & 15);
    int k = ks * 32 + ((l >> 4) << 3) + j;
    w_swz[idx] = f2bf(qkv_w[row * 288 + k]);
  } else if (idx < 248832 + 27648) {
    int t = idx - 248832;
    int f = t >> 9, r = t & 511;
    int l = r >> 3, j = r & 7;
    int h = f / 18, rem = f - h * 18;
    int nt = rem / 3, ks = rem - nt * 3;
    int c = nt * 16 + (l & 15);
    int d = ks * 32 + ((l >> 4) << 3) + j;
    pw_swz[t] = f2bf(proj_w[c * 288 + h * 96 + d]);
  } else if (idx < 248832 + 27648 + 7203) {
    int t = idx - (248832 + 27648);
    int h = t / 2401, r = t - h * 2401;
    bias3[t] = bias_table[rel_index[r] * 3 + h];
  }
}

// ---------------- fused window attention ----------------
// LDS layout (unsigned short elements):
//   A  [64][296]  xy bf16 (rows>=49 zero)          0     .. 18944
//   Q  [49][104]  q bf16 (pre-scaled) / reused as O 18944 .. 24040
//   K  [49][104]  k bf16                            24040 .. 29136
//   Vt [96][72]   v transposed (d-major)            29136 .. 36048
//   P  [64][72]   softmax probs bf16                36048 .. 40656
#define A_OFF 0
#define Q_OFF 18944
#define K_OFF 24040
#define VT_OFF 29136
#define P_OFF 36048
#define SMEM_TOT 40656

__global__ __launch_bounds__(256, 2)
void wattn_kernel(const float* __restrict__ x, const float* __restrict__ y,
                  const float* __restrict__ z, const float* __restrict__ mask,
                  const float* __restrict__ qkv_b, const float* __restrict__ proj_b,
                  const unsigned short* __restrict__ w_swz,
                  const unsigned short* __restrict__ pw_swz,
                  const float* __restrict__ bias3,
                  float* __restrict__ out, int nW)
{
  __shared__ unsigned short smem[SMEM_TOT];
  const int b = blockIdx.x;
  const int tid = threadIdx.x;
  const int wv = tid >> 6;
  const int lane = tid & 63;
  const int g = lane >> 4;
  const int cl = lane & 15;
  const int kblk = g << 3;
  const int widx = b % nW;

  // ---- stage concat(x,y,z) window tile -> LDS bf16 ----
  for (int idx = tid; idx < 64 * 72; idx += 256) {
    int row = idx / 72;
    int col = (idx - row * 72) << 2;
    float4 v = make_float4(0.f, 0.f, 0.f, 0.f);
    if (row < NTOK) {
      size_t base = ((size_t)b * NTOK + row) * 96;
      if (col < 96)       v = *(const float4*)(x + base + col);
      else if (col < 192) v = *(const float4*)(y + base + col - 96);
      else                v = *(const float4*)(z + base + col - 192);
    }
    u16x4 s;
    s[0] = f2bf(v.x); s[1] = f2bf(v.y); s[2] = f2bf(v.z); s[3] = f2bf(v.w);
    *(u16x4*)&smem[A_OFF + row * 296 + col] = s;
  }
  __syncthreads();

  f32x4 outacc[6];
  #pragma unroll
  for (int i = 0; i < 6; ++i) outacc[i] = f32x4{0.f, 0.f, 0.f, 0.f};

  const int nmine = (wv < 2) ? 5 : 4;      // 18 n-tiles split 5/5/4/4 across waves
  const int nrow_base = wv * 16 + (g << 2);

  for (int h = 0; h < 3; ++h) {
    // ---- QKV GEMM: [64x288] @ W_head^T -> q,k,v [64x96] each ----
    f32x4 acc[5][4];
    #pragma unroll
    for (int i = 0; i < 5; ++i)
      #pragma unroll
      for (int m = 0; m < 4; ++m) acc[i][m] = f32x4{0.f, 0.f, 0.f, 0.f};

    #pragma unroll
    for (int ks = 0; ks < 9; ++ks) {
      short8 af[4];
      #pragma unroll
      for (int m = 0; m < 4; ++m)
        af[m] = *(const short8*)&smem[A_OFF + (m * 16 + cl) * 296 + ks * 32 + kblk];
      #pragma unroll
      for (int i = 0; i < 5; ++i) {
        if (i < nmine) {
          int ntl = wv + 4 * i;            // 0..17
          int s = ntl / 6;                 // 0=q 1=k 2=v
          int ntd = ntl - s * 6;           // d-tile 0..5
          int gnt = s * 18 + h * 6 + ntd;  // global W n-tile
          short8 bf = *(const short8*)&w_swz[(size_t)(gnt * 9 + ks) * 512 + lane * 8];
          #pragma unroll
          for (int m = 0; m < 4; ++m)
            acc[i][m] = __builtin_amdgcn_mfma_f32_16x16x32_bf16(af[m], bf, acc[i][m], 0, 0, 0);
        }
      }
    }

    __syncthreads();  // all waves done reading prev head's Q/K/Vt/P

    #pragma unroll
    for (int i = 0; i < 5; ++i) {
      if (i < nmine) {
        int ntl = wv + 4 * i;
        int s = ntl / 6;
        int ntd = ntl - s * 6;
        float bq = qkv_b[s * 288 + h * 96 + ntd * 16 + cl];
        #pragma unroll
        for (int m = 0; m < 4; ++m) {
          #pragma unroll
          for (int r = 0; r < 4; ++r) {
            int row = m * 16 + (g << 2) + r;
            int col = ntd * 16 + cl;
            float val = acc[i][m][r] + bq;
            if (s == 0) {
              if (row < NTOK) smem[Q_OFF + row * 104 + col] = f2bf(val * 0.1767766952966369f);
            } else if (s == 1) {
              if (row < NTOK) smem[K_OFF + row * 104 + col] = f2bf(val);
            } else {
              smem[VT_OFF + col * 72 + row] = f2bf(val);  // transposed: all 64 rows (zeros beyond 49)
            }
          }
        }
      }
    }
    __syncthreads();

    // ---- S = Q @ K^T  (wave owns S rows [16wv,16wv+16)) ----
    f32x4 sacc[4];
    #pragma unroll
    for (int nt = 0; nt < 4; ++nt) sacc[nt] = f32x4{0.f, 0.f, 0.f, 0.f};
    #pragma unroll
    for (int ks = 0; ks < 3; ++ks) {
      short8 aq = *(const short8*)&smem[Q_OFF + (wv * 16 + cl) * 104 + ks * 32 + kblk];
      #pragma unroll
      for (int nt = 0; nt < 4; ++nt) {
        short8 bk = *(const short8*)&smem[K_OFF + (nt * 16 + cl) * 104 + ks * 32 + kblk];
        sacc[nt] = __builtin_amdgcn_mfma_f32_16x16x32_bf16(aq, bk, sacc[nt], 0, 0, 0);
      }
    }

    // ---- bias + mask + softmax (fp32, 16-lane parallel reduce per row) ----
    #pragma unroll
    for (int r = 0; r < 4; ++r) {
      int n = nrow_base + r;
      int nn = n < NTOK ? n : NTOK - 1;
      const float* brow = bias3 + h * 2401 + nn * 49;
      const float* mrow = mask + ((size_t)widx * NTOK + nn) * NTOK;
      float vals[4];
      float mx = -1e30f;
      #pragma unroll
      for (int nt = 0; nt < 4; ++nt) {
        int m = nt * 16 + cl;
        float sv = -1e30f;
        if (m < NTOK) sv = sacc[nt][r] + brow[m] + mrow[m];
        vals[nt] = sv;
        mx = fmaxf(mx, sv);
      }
      mx = fmaxf(mx, __shfl_xor(mx, 1));
      mx = fmaxf(mx, __shfl_xor(mx, 2));
      mx = fmaxf(mx, __shfl_xor(mx, 4));
      mx = fmaxf(mx, __shfl_xor(mx, 8));
      float sum = 0.f;
      #pragma unroll
      for (int nt = 0; nt < 4; ++nt) {
        float e = __expf(vals[nt] - mx);
        vals[nt] = e;
        sum += e;
      }
      sum += __shfl_xor(sum, 1);
      sum += __shfl_xor(sum, 2);
      sum += __shfl_xor(sum, 4);
      sum += __shfl_xor(sum, 8);
      float inv = 1.f / sum;
      #pragma unroll
      for (int nt = 0; nt < 4; ++nt)
        smem[P_OFF + n * 72 + nt * 16 + cl] = f2bf(vals[nt] * inv);
    }
    // wave-local P write->read; no barrier needed (each wave touches only its own rows)

    // ---- O = P @ V ----
    f32x4 oacc[6];
    #pragma unroll
    for (int nt = 0; nt < 6; ++nt) oacc[nt] = f32x4{0.f, 0.f, 0.f, 0.f};
    #pragma unroll
    for (int ks = 0; ks < 2; ++ks) {
      short8 ap = *(const short8*)&smem[P_OFF + (wv * 16 + cl) * 72 + ks * 32 + kblk];
      #pragma unroll
      for (int nt = 0; nt < 6; ++nt) {
        short8 bv = *(const short8*)&smem[VT_OFF + (nt * 16 + cl) * 72 + ks * 32 + kblk];
        oacc[nt] = __builtin_amdgcn_mfma_f32_16x16x32_bf16(ap, bv, oacc[nt], 0, 0, 0);
      }
    }
    // O -> Q region (wave-local rows only)
    #pragma unroll
    for (int nt = 0; nt < 6; ++nt) {
      #pragma unroll
      for (int r = 0; r < 4; ++r) {
        int row = nrow_base + r;
        if (row < NTOK) smem[Q_OFF + row * 104 + nt * 16 + cl] = f2bf(oacc[nt][r]);
      }
    }

    // ---- proj partial: outacc += O @ proj_w_head^T ----
    #pragma unroll
    for (int ks = 0; ks < 3; ++ks) {
      short8 ao = *(const short8*)&smem[Q_OFF + (wv * 16 + cl) * 104 + ks * 32 + kblk];
      #pragma unroll
      for (int nt = 0; nt < 6; ++nt) {
        short8 bp = *(const short8*)&pw_swz[(size_t)((h * 6 + nt) * 3 + ks) * 512 + lane * 8];
        outacc[nt] = __builtin_amdgcn_mfma_f32_16x16x32_bf16(ao, bp, outacc[nt], 0, 0, 0);
      }
    }
  }

  // ---- epilogue: + proj_b, store fp32 ----
  #pragma unroll
  for (int nt = 0; nt < 6; ++nt) {
    float pb = proj_b[nt * 16 + cl];
    #pragma unroll
    for (int r = 0; r < 4; ++r) {
      int n = nrow_base + r;
      if (n < NTOK)
        out[((size_t)b * NTOK + n) * 96 + nt * 16 + cl] = outacc[nt][r] + pb;
    }
  }
}

extern "C" void kernel_launch(void* const* d_in, const int* in_sizes, int n_in,
                              void* d_out, int out_size, void* d_ws, size_t ws_size,
                              hipStream_t stream) {
  const float* x          = (const float*)d_in[0];
  const float* y          = (const float*)d_in[1];
  const float* z          = (const float*)d_in[2];
  const float* mask       = (const float*)d_in[3];
  const float* qkv_w      = (const float*)d_in[4];
  const float* qkv_b      = (const float*)d_in[5];
  const float* proj_w     = (const float*)d_in[6];
  const float* proj_b     = (const float*)d_in[7];
  const float* bias_table = (const float*)d_in[8];
  const int*   rel_index  = (const int*)d_in[9];

  int B  = in_sizes[0] / (NTOK * 96);
  int nW = in_sizes[3] / (NTOK * NTOK);

  unsigned short* w_swz  = (unsigned short*)d_ws;
  unsigned short* pw_swz = w_swz + 248832;
  float*          bias3  = (float*)(pw_swz + 27648);

  prep_kernel<<<1109, 256, 0, stream>>>(qkv_w, proj_w, bias_table, rel_index,
                                        w_swz, pw_swz, bias3);
  wattn_kernel<<<B, 256, 0, stream>>>(x, y, z, mask, qkv_b, proj_b,
                                      w_swz, pw_swz, bias3, (float*)d_out, nW);
}

// Round 2
// 566.408 us; speedup vs baseline: 1.1467x; 1.1467x over previous
//
#include <hip/hip_runtime.h>

#define NTOK 49

typedef __attribute__((ext_vector_type(8))) short short8;
typedef __attribute__((ext_vector_type(4))) float f32x4;
typedef __attribute__((ext_vector_type(4))) unsigned short u16x4;

__device__ __forceinline__ unsigned short f2bf(float f) {
  union { float f; unsigned u; } v; v.f = f;
  unsigned r = v.u + 0x7FFFu + ((v.u >> 16) & 1u);  // round-to-nearest-even
  return (unsigned short)(r >> 16);
}

// ---------------- prep: swizzle weights to bf16 MFMA-fragment order + bias gather ----------------
// w_swz  : [54 ntiles][9 ksteps][64 lanes][8] bf16   (qkv_w, 864x288)
// pw_swz : [3 h][6 nt][3 ks][64 lanes][8]   bf16     (proj_w per-head slices, 96x96)
// bias3  : [3][49][49] f32
__global__ void prep_kernel(const float* __restrict__ qkv_w,
                            const float* __restrict__ proj_w,
                            const float* __restrict__ bias_table,
                            const int* __restrict__ rel_index,
                            unsigned short* __restrict__ w_swz,
                            unsigned short* __restrict__ pw_swz,
                            float* __restrict__ bias3)
{
  int idx = blockIdx.x * 256 + threadIdx.x;
  if (idx < 248832) {
    int f = idx >> 9, r = idx & 511;
    int l = r >> 3, j = r & 7;
    int nt = f / 9, ks = f - nt * 9;
    int row = nt * 16 + (l & 15);
    int k = ks * 32 + ((l >> 4) << 3) + j;
    w_swz[idx] = f2bf(qkv_w[row * 288 + k]);
  } else if (idx < 248832 + 27648) {
    int t = idx - 248832;
    int f = t >> 9, r = t & 511;
    int l = r >> 3, j = r & 7;
    int h = f / 18, rem = f - h * 18;
    int nt = rem / 3, ks = rem - nt * 3;
    int c = nt * 16 + (l & 15);
    int d = ks * 32 + ((l >> 4) << 3) + j;
    pw_swz[t] = f2bf(proj_w[c * 288 + h * 96 + d]);
  } else if (idx < 248832 + 27648 + 7203) {
    int t = idx - (248832 + 27648);
    int h = t / 2401, r = t - h * 2401;
    bias3[t] = bias_table[rel_index[r] * 3 + h];
  }
}

// ---------------- fused window attention, 8 waves ----------------
// LDS (shorts):
//   A  [64][296]  xyz bf16 (rows>=49 zeroed)    0     .. 18944
//   Q  [49][104]  q bf16 pre-scaled; O overlays K region after S
//   K  [49][104]  k bf16  (O written here during PV)
//   Vt [96][72]   v transposed (d-major, 64 token cols)
//   P  [64][72]   softmax probs bf16
#define A_OFF 0
#define Q_OFF 18944
#define K_OFF 24040
#define VT_OFF 29136
#define P_OFF 36048
#define SMEM_TOT 40656   // 81312 bytes -> 2 blocks/CU

__global__ __launch_bounds__(512, 4)
void wattn_kernel(const float* __restrict__ x, const float* __restrict__ y,
                  const float* __restrict__ z, const float* __restrict__ mask,
                  const float* __restrict__ qkv_b, const float* __restrict__ proj_b,
                  const unsigned short* __restrict__ w_swz,
                  const unsigned short* __restrict__ pw_swz,
                  const float* __restrict__ bias3,
                  float* __restrict__ out, int nW)
{
  __shared__ unsigned short smem[SMEM_TOT];
  const int b = blockIdx.x;
  const int tid = threadIdx.x;
  const int w = tid >> 6;        // 0..7
  const int lane = tid & 63;
  const int g = lane >> 4;
  const int cl = lane & 15;
  const int kblk = g << 3;
  const int widx = b % nW;
  const int t4 = w & 3;          // row-tile for S/PV/proj
  const int hf = w >> 2;         // half split

  // ---- stage concat(x,y,z) -> LDS bf16 (rows>=49 zero) ----
  #pragma unroll
  for (int it = 0; it < 9; ++it) {
    int idx = tid + it * 512;            // 0..4607 over [64 rows][72 float4]
    int row = idx / 72;
    int c4 = idx - row * 72;
    int col = c4 << 2;
    float4 v = make_float4(0.f, 0.f, 0.f, 0.f);
    if (row < NTOK) {
      size_t base = ((size_t)b * NTOK + row) * 96;
      if (col < 96)       v = *(const float4*)(x + base + col);
      else if (col < 192) v = *(const float4*)(y + base + col - 96);
      else                v = *(const float4*)(z + base + col - 192);
    }
    u16x4 s;
    s[0] = f2bf(v.x); s[1] = f2bf(v.y); s[2] = f2bf(v.z); s[3] = f2bf(v.w);
    *(u16x4*)&smem[A_OFF + row * 296 + col] = s;
  }
  __syncthreads();

  // QKV n-tile split: waves 0,1 -> q (3 tiles each); 2,3,4 -> k (2); 5,6,7 -> v (2)
  const int start = (w < 2) ? 3 * w : 6 + 2 * (w - 2);
  const int cnt   = (w < 2) ? 3 : 2;

  f32x4 outacc[3];
  #pragma unroll
  for (int i = 0; i < 3; ++i) outacc[i] = f32x4{0.f, 0.f, 0.f, 0.f};

  for (int h = 0; h < 3; ++h) {
    // ---- QKV GEMM ----
    f32x4 acc[3][4];
    #pragma unroll
    for (int i = 0; i < 3; ++i)
      #pragma unroll
      for (int m = 0; m < 4; ++m) acc[i][m] = f32x4{0.f, 0.f, 0.f, 0.f};

    #pragma unroll
    for (int ks = 0; ks < 9; ++ks) {
      short8 af[4];
      #pragma unroll
      for (int m = 0; m < 4; ++m)
        af[m] = *(const short8*)&smem[A_OFF + (m * 16 + cl) * 296 + ks * 32 + kblk];
      #pragma unroll
      for (int i = 0; i < 3; ++i) {
        if (i < cnt) {
          int ntl = start + i;
          int s = ntl / 6;
          int ntd = ntl - s * 6;
          int gnt = s * 18 + h * 6 + ntd;
          short8 bf = *(const short8*)&w_swz[(size_t)(gnt * 9 + ks) * 512 + lane * 8];
          #pragma unroll
          for (int m = 0; m < 4; ++m)
            acc[i][m] = __builtin_amdgcn_mfma_f32_16x16x32_bf16(af[m], bf, acc[i][m], 0, 0, 0);
        }
      }
    }

    __syncthreads();  // prev head's S/PV/proj LDS reads all complete

    // ---- writeback q/k/v to LDS ----
    #pragma unroll
    for (int i = 0; i < 3; ++i) {
      if (i < cnt) {
        int ntl = start + i;
        int s = ntl / 6;
        int ntd = ntl - s * 6;
        float bq = qkv_b[s * 288 + h * 96 + ntd * 16 + cl];
        if (s == 2) {            // V: transposed, packed b64 writes
          #pragma unroll
          for (int m = 0; m < 4; ++m) {
            u16x4 pk;
            #pragma unroll
            for (int r = 0; r < 4; ++r) pk[r] = f2bf(acc[i][m][r] + bq);
            *(u16x4*)&smem[VT_OFF + (ntd * 16 + cl) * 72 + m * 16 + (g << 2)] = pk;
          }
        } else {
          const int off = s ? K_OFF : Q_OFF;
          const float sc = s ? 1.f : 0.1767766952966369f;
          #pragma unroll
          for (int m = 0; m < 4; ++m) {
            #pragma unroll
            for (int r = 0; r < 4; ++r) {
              int row = m * 16 + (g << 2) + r;
              if (row < NTOK)
                smem[off + row * 104 + ntd * 16 + cl] = f2bf((acc[i][m][r] + bq) * sc);
            }
          }
        }
      }
    }
    __syncthreads();

    // ---- prefetch bias+mask rows for my 2 softmax rows (hide under S MFMAs) ----
    float bi[2][4], mk[2][4];
    #pragma unroll
    for (int rr = 0; rr < 2; ++rr) {
      int n = t4 * 16 + (g << 2) + 2 * hf + rr;
      int nn = n < NTOK ? n : NTOK - 1;
      const float* brow = bias3 + h * 2401 + nn * 49;
      const float* mrow = mask + ((size_t)widx * NTOK + nn) * NTOK;
      #pragma unroll
      for (int nt = 0; nt < 4; ++nt) {
        int m = nt * 16 + cl;
        int mm = m < NTOK ? m : NTOK - 1;
        bi[rr][nt] = brow[mm];
        mk[rr][nt] = mrow[mm];
      }
    }

    // ---- S = Q K^T (each wave-pair duplicates its row-tile) ----
    f32x4 sacc[4];
    #pragma unroll
    for (int nt = 0; nt < 4; ++nt) sacc[nt] = f32x4{0.f, 0.f, 0.f, 0.f};
    #pragma unroll
    for (int ks = 0; ks < 3; ++ks) {
      short8 aq = *(const short8*)&smem[Q_OFF + (t4 * 16 + cl) * 104 + ks * 32 + kblk];
      #pragma unroll
      for (int nt = 0; nt < 4; ++nt) {
        short8 bk = *(const short8*)&smem[K_OFF + (nt * 16 + cl) * 104 + ks * 32 + kblk];
        sacc[nt] = __builtin_amdgcn_mfma_f32_16x16x32_bf16(aq, bk, sacc[nt], 0, 0, 0);
      }
    }

    // ---- softmax: wave handles rows r = 2*hf .. 2*hf+1 of its tile ----
    #pragma unroll
    for (int r = 0; r < 4; ++r) {
      if ((r >> 1) != hf) continue;     // uniform; r stays compile-time
      int rr = r & 1;
      int n = t4 * 16 + (g << 2) + r;
      float vals[4];
      float mx = -1e30f;
      #pragma unroll
      for (int nt = 0; nt < 4; ++nt) {
        int m = nt * 16 + cl;
        float sv = -1e30f;
        if (m < NTOK) sv = sacc[nt][r] + bi[rr][nt] + mk[rr][nt];
        vals[nt] = sv;
        mx = fmaxf(mx, sv);
      }
      mx = fmaxf(mx, __shfl_xor(mx, 1));
      mx = fmaxf(mx, __shfl_xor(mx, 2));
      mx = fmaxf(mx, __shfl_xor(mx, 4));
      mx = fmaxf(mx, __shfl_xor(mx, 8));
      float sum = 0.f;
      #pragma unroll
      for (int nt = 0; nt < 4; ++nt) {
        float e = __expf(vals[nt] - mx);
        vals[nt] = e;
        sum += e;
      }
      sum += __shfl_xor(sum, 1);
      sum += __shfl_xor(sum, 2);
      sum += __shfl_xor(sum, 4);
      sum += __shfl_xor(sum, 8);
      float inv = 1.f / sum;
      #pragma unroll
      for (int nt = 0; nt < 4; ++nt)
        smem[P_OFF + n * 72 + nt * 16 + cl] = f2bf(vals[nt] * inv);
    }
    __syncthreads();

    // ---- O = P @ V : wave -> (row-tile t4, nt = hf*3+jj); O overlays K region ----
    f32x4 oacc[3];
    #pragma unroll
    for (int jj = 0; jj < 3; ++jj) oacc[jj] = f32x4{0.f, 0.f, 0.f, 0.f};
    #pragma unroll
    for (int ks = 0; ks < 2; ++ks) {
      short8 ap = *(const short8*)&smem[P_OFF + (t4 * 16 + cl) * 72 + ks * 32 + kblk];
      #pragma unroll
      for (int jj = 0; jj < 3; ++jj) {
        int nt = hf * 3 + jj;
        short8 bv = *(const short8*)&smem[VT_OFF + (nt * 16 + cl) * 72 + ks * 32 + kblk];
        oacc[jj] = __builtin_amdgcn_mfma_f32_16x16x32_bf16(ap, bv, oacc[jj], 0, 0, 0);
      }
    }
    #pragma unroll
    for (int jj = 0; jj < 3; ++jj) {
      #pragma unroll
      for (int r = 0; r < 4; ++r) {
        int row = t4 * 16 + (g << 2) + r;
        if (row < NTOK)
          smem[K_OFF + row * 104 + (hf * 3 + jj) * 16 + cl] = f2bf(oacc[jj][r]);
      }
    }
    __syncthreads();

    // ---- proj partial: outacc += O @ proj_w_head^T ----
    #pragma unroll
    for (int ks = 0; ks < 3; ++ks) {
      short8 ao = *(const short8*)&smem[K_OFF + (t4 * 16 + cl) * 104 + ks * 32 + kblk];
      #pragma unroll
      for (int jj = 0; jj < 3; ++jj) {
        int nt = hf * 3 + jj;
        short8 bp = *(const short8*)&pw_swz[(size_t)((h * 6 + nt) * 3 + ks) * 512 + lane * 8];
        outacc[jj] = __builtin_amdgcn_mfma_f32_16x16x32_bf16(ao, bp, outacc[jj], 0, 0, 0);
      }
    }
  }

  // ---- epilogue ----
  #pragma unroll
  for (int jj = 0; jj < 3; ++jj) {
    float pb = proj_b[(hf * 3 + jj) * 16 + cl];
    #pragma unroll
    for (int r = 0; r < 4; ++r) {
      int n = t4 * 16 + (g << 2) + r;
      if (n < NTOK)
        out[((size_t)b * NTOK + n) * 96 + (hf * 3 + jj) * 16 + cl] = outacc[jj][r] + pb;
    }
  }
}

extern "C" void kernel_launch(void* const* d_in, const int* in_sizes, int n_in,
                              void* d_out, int out_size, void* d_ws, size_t ws_size,
                              hipStream_t stream) {
  const float* x          = (const float*)d_in[0];
  const float* y          = (const float*)d_in[1];
  const float* z          = (const float*)d_in[2];
  const float* mask       = (const float*)d_in[3];
  const float* qkv_w      = (const float*)d_in[4];
  const float* qkv_b      = (const float*)d_in[5];
  const float* proj_w     = (const float*)d_in[6];
  const float* proj_b     = (const float*)d_in[7];
  const float* bias_table = (const float*)d_in[8];
  const int*   rel_index  = (const int*)d_in[9];

  int B  = in_sizes[0] / (NTOK * 96);
  int nW = in_sizes[3] / (NTOK * NTOK);

  unsigned short* w_swz  = (unsigned short*)d_ws;
  unsigned short* pw_swz = w_swz + 248832;
  float*          bias3  = (float*)(pw_swz + 27648);

  prep_kernel<<<1109, 256, 0, stream>>>(qkv_w, proj_w, bias_table, rel_index,
                                        w_swz, pw_swz, bias3);
  wattn_kernel<<<B, 512, 0, stream>>>(x, y, z, mask, qkv_b, proj_b,
                                      w_swz, pw_swz, bias3, (float*)d_out, nW);
}

// Round 3
// 491.749 us; speedup vs baseline: 1.3207x; 1.1518x over previous
//
#include <hip/hip_runtime.h>

#define NTOK 49

typedef __attribute__((ext_vector_type(8))) short short8;
typedef __attribute__((ext_vector_type(4))) float f32x4;
typedef __attribute__((ext_vector_type(4))) unsigned short u16x4;

__device__ __forceinline__ unsigned short f2bf(float f) {
  union { float f; unsigned u; } v; v.f = f;
  unsigned r = v.u + 0x7FFFu + ((v.u >> 16) & 1u);  // round-to-nearest-even
  return (unsigned short)(r >> 16);
}

// ---------------- prep: swizzle weights to bf16 MFMA-fragment order + bias gather ----------------
// w_swz  : [54 ntiles][9 ksteps][64 lanes][8] bf16   (qkv_w, 864x288)
// pw_swz : [3 h][6 nt][3 ks][64 lanes][8]   bf16     (proj_w per-head slices, 96x96)
// bias3  : [3][49][49] f32
__global__ void prep_kernel(const float* __restrict__ qkv_w,
                            const float* __restrict__ proj_w,
                            const float* __restrict__ bias_table,
                            const int* __restrict__ rel_index,
                            unsigned short* __restrict__ w_swz,
                            unsigned short* __restrict__ pw_swz,
                            float* __restrict__ bias3)
{
  int idx = blockIdx.x * 256 + threadIdx.x;
  if (idx < 248832) {
    int f = idx >> 9, r = idx & 511;
    int l = r >> 3, j = r & 7;
    int nt = f / 9, ks = f - nt * 9;
    int row = nt * 16 + (l & 15);
    int k = ks * 32 + ((l >> 4) << 3) + j;
    w_swz[idx] = f2bf(qkv_w[row * 288 + k]);
  } else if (idx < 248832 + 27648) {
    int t = idx - 248832;
    int f = t >> 9, r = t & 511;
    int l = r >> 3, j = r & 7;
    int h = f / 18, rem = f - h * 18;
    int nt = rem / 3, ks = rem - nt * 3;
    int c = nt * 16 + (l & 15);
    int d = ks * 32 + ((l >> 4) << 3) + j;
    pw_swz[t] = f2bf(proj_w[c * 288 + h * 96 + d]);
  } else if (idx < 248832 + 27648 + 7203) {
    int t = idx - (248832 + 27648);
    int h = t / 2401, r = t - h * 2401;
    bias3[t] = bias_table[rel_index[r] * 3 + h];
  }
}

// ---------------- fused window attention, 8 waves, low register pressure ----------------
// LDS (shorts):
//   A  [64][296]  xyz bf16 (rows>=49 zeroed)
//   Q  [49][104]  q bf16 pre-scaled
//   K  [49][104]  k bf16  (O overlays during PV)
//   Vt [96][72]   v transposed (d-major, 64 token cols)
//   P  [64][72]   softmax probs bf16
#define A_OFF 0
#define Q_OFF 18944
#define K_OFF 24040
#define VT_OFF 29136
#define P_OFF 36048
#define SMEM_TOT 40656   // 81312 bytes -> 2 blocks/CU

__global__ __launch_bounds__(512, 4)
void wattn_kernel(const float* __restrict__ x, const float* __restrict__ y,
                  const float* __restrict__ z, const float* __restrict__ mask,
                  const float* __restrict__ qkv_b, const float* __restrict__ proj_b,
                  const unsigned short* __restrict__ w_swz,
                  const unsigned short* __restrict__ pw_swz,
                  const float* __restrict__ bias3,
                  float* __restrict__ out, int nW)
{
  __shared__ unsigned short smem[SMEM_TOT];
  const int b = blockIdx.x;
  const int tid = threadIdx.x;
  const int w = tid >> 6;        // 0..7
  const int lane = tid & 63;
  const int g = lane >> 4;
  const int cl = lane & 15;
  const int kblk = g << 3;
  const int widx = b % nW;
  const int t4 = w & 3;          // row-tile for S/PV/proj
  const int hf = w >> 2;         // half split

  // ---- stage concat(x,y,z) -> LDS bf16 (rows>=49 zero) ----
  #pragma unroll
  for (int it = 0; it < 9; ++it) {
    int idx = tid + it * 512;            // [64 rows][72 float4]
    int row = idx / 72;
    int c4 = idx - row * 72;
    int col = c4 << 2;
    float4 v = make_float4(0.f, 0.f, 0.f, 0.f);
    if (row < NTOK) {
      size_t base = ((size_t)b * NTOK + row) * 96;
      if (col < 96)       v = *(const float4*)(x + base + col);
      else if (col < 192) v = *(const float4*)(y + base + col - 96);
      else                v = *(const float4*)(z + base + col - 192);
    }
    u16x4 s;
    s[0] = f2bf(v.x); s[1] = f2bf(v.y); s[2] = f2bf(v.z); s[3] = f2bf(v.w);
    *(u16x4*)&smem[A_OFF + row * 296 + col] = s;
  }

  // QKV pass-1 tile constants (tiles 0..15): wave owns 2w, 2w+1
  const int tA = 2 * w, tB = 2 * w + 1;
  const int sA = (tA >= 12) ? 2 : ((tA >= 6) ? 1 : 0);
  const int sB = (tB >= 12) ? 2 : ((tB >= 6) ? 1 : 0);
  const int dA = tA - 6 * sA, dB = tB - 6 * sB;
  // pass-2: all-V tiles 16,17 split by m-tile across 8 waves
  const int mw = w & 3;
  const int d2 = 4 + (w >> 2);

  f32x4 outacc[3];
  #pragma unroll
  for (int i = 0; i < 3; ++i) outacc[i] = f32x4{0.f, 0.f, 0.f, 0.f};

  __syncthreads();

  for (int h = 0; h < 3; ++h) {
    // all reads of previous head's Q/K/Vt/P/O complete before overwrite
    __syncthreads();

    // ---- QKV pass 1: two tiles per wave ----
    {
      f32x4 accA[4], accB[4];
      #pragma unroll
      for (int m = 0; m < 4; ++m) { accA[m] = f32x4{0,0,0,0}; accB[m] = f32x4{0,0,0,0}; }
      const unsigned short* wpA = w_swz + (size_t)(sA * 18 + h * 6 + dA) * 9 * 512 + lane * 8;
      const unsigned short* wpB = w_swz + (size_t)(sB * 18 + h * 6 + dB) * 9 * 512 + lane * 8;
      #pragma unroll
      for (int ks = 0; ks < 9; ++ks) {
        short8 af[4];
        #pragma unroll
        for (int m = 0; m < 4; ++m)
          af[m] = *(const short8*)&smem[A_OFF + (m * 16 + cl) * 296 + ks * 32 + kblk];
        short8 bfA = *(const short8*)(wpA + ks * 512);
        short8 bfB = *(const short8*)(wpB + ks * 512);
        #pragma unroll
        for (int m = 0; m < 4; ++m)
          accA[m] = __builtin_amdgcn_mfma_f32_16x16x32_bf16(af[m], bfA, accA[m], 0, 0, 0);
        #pragma unroll
        for (int m = 0; m < 4; ++m)
          accB[m] = __builtin_amdgcn_mfma_f32_16x16x32_bf16(af[m], bfB, accB[m], 0, 0, 0);
      }
      // writeback A then B
      #pragma unroll
      for (int t = 0; t < 2; ++t) {
        const int s = t ? sB : sA;
        const int ntd = t ? dB : dA;
        float bq = qkv_b[s * 288 + h * 96 + ntd * 16 + cl];
        if (s == 2) {
          #pragma unroll
          for (int m = 0; m < 4; ++m) {
            u16x4 pk;
            #pragma unroll
            for (int r = 0; r < 4; ++r) pk[r] = f2bf((t ? accB[m][r] : accA[m][r]) + bq);
            *(u16x4*)&smem[VT_OFF + (ntd * 16 + cl) * 72 + m * 16 + (g << 2)] = pk;
          }
        } else {
          const int off = s ? K_OFF : Q_OFF;
          const float sc = s ? 1.f : 0.1767766952966369f;
          #pragma unroll
          for (int m = 0; m < 4; ++m) {
            #pragma unroll
            for (int r = 0; r < 4; ++r) {
              int row = m * 16 + (g << 2) + r;
              if (row < NTOK)
                smem[off + row * 104 + ntd * 16 + cl] = f2bf(((t ? accB[m][r] : accA[m][r]) + bq) * sc);
            }
          }
        }
      }
    }

    // ---- QKV pass 2: V tiles 16,17, one m-tile per wave ----
    {
      f32x4 acc2 = f32x4{0, 0, 0, 0};
      const unsigned short* wpC = w_swz + (size_t)(36 + h * 6 + d2) * 9 * 512 + lane * 8;
      #pragma unroll
      for (int ks = 0; ks < 9; ++ks) {
        short8 af = *(const short8*)&smem[A_OFF + (mw * 16 + cl) * 296 + ks * 32 + kblk];
        short8 bf = *(const short8*)(wpC + ks * 512);
        acc2 = __builtin_amdgcn_mfma_f32_16x16x32_bf16(af, bf, acc2, 0, 0, 0);
      }
      float bq = qkv_b[2 * 288 + h * 96 + d2 * 16 + cl];
      u16x4 pk;
      #pragma unroll
      for (int r = 0; r < 4; ++r) pk[r] = f2bf(acc2[r] + bq);
      *(u16x4*)&smem[VT_OFF + (d2 * 16 + cl) * 72 + mw * 16 + (g << 2)] = pk;
    }
    __syncthreads();

    // ---- S = Q K^T (wave-pair duplicates its row-tile) ----
    f32x4 sacc[4];
    #pragma unroll
    for (int nt = 0; nt < 4; ++nt) sacc[nt] = f32x4{0.f, 0.f, 0.f, 0.f};
    #pragma unroll
    for (int ks = 0; ks < 3; ++ks) {
      short8 aq = *(const short8*)&smem[Q_OFF + (t4 * 16 + cl) * 104 + ks * 32 + kblk];
      #pragma unroll
      for (int nt = 0; nt < 4; ++nt) {
        short8 bk = *(const short8*)&smem[K_OFF + (nt * 16 + cl) * 104 + ks * 32 + kblk];
        sacc[nt] = __builtin_amdgcn_mfma_f32_16x16x32_bf16(aq, bk, sacc[nt], 0, 0, 0);
      }
    }

    // ---- softmax: wave handles rows r in {2hf, 2hf+1} of its tile ----
    #pragma unroll
    for (int r = 0; r < 4; ++r) {
      if ((r >> 1) != hf) continue;     // uniform; r compile-time
      int n = t4 * 16 + (g << 2) + r;
      int nn = n < NTOK ? n : NTOK - 1;
      const float* brow = bias3 + h * 2401 + nn * 49;
      const float* mrow = mask + ((size_t)widx * NTOK + nn) * NTOK;
      float vals[4];
      float mx = -1e30f;
      #pragma unroll
      for (int nt = 0; nt < 4; ++nt) {
        int m = nt * 16 + cl;
        int mm = m < NTOK ? m : NTOK - 1;
        float sv = -1e30f;
        if (m < NTOK) sv = sacc[nt][r] + brow[mm] + mrow[mm];
        vals[nt] = sv;
        mx = fmaxf(mx, sv);
      }
      mx = fmaxf(mx, __shfl_xor(mx, 1));
      mx = fmaxf(mx, __shfl_xor(mx, 2));
      mx = fmaxf(mx, __shfl_xor(mx, 4));
      mx = fmaxf(mx, __shfl_xor(mx, 8));
      float sum = 0.f;
      #pragma unroll
      for (int nt = 0; nt < 4; ++nt) {
        float e = __expf(vals[nt] - mx);
        vals[nt] = e;
        sum += e;
      }
      sum += __shfl_xor(sum, 1);
      sum += __shfl_xor(sum, 2);
      sum += __shfl_xor(sum, 4);
      sum += __shfl_xor(sum, 8);
      float inv = 1.f / sum;
      #pragma unroll
      for (int nt = 0; nt < 4; ++nt)
        smem[P_OFF + n * 72 + nt * 16 + cl] = f2bf(vals[nt] * inv);
    }
    __syncthreads();

    // ---- O = P @ V : wave -> (row-tile t4, nt = hf*3+jj); O overlays K region ----
    f32x4 oacc[3];
    #pragma unroll
    for (int jj = 0; jj < 3; ++jj) oacc[jj] = f32x4{0.f, 0.f, 0.f, 0.f};
    #pragma unroll
    for (int ks = 0; ks < 2; ++ks) {
      short8 ap = *(const short8*)&smem[P_OFF + (t4 * 16 + cl) * 72 + ks * 32 + kblk];
      #pragma unroll
      for (int jj = 0; jj < 3; ++jj) {
        int nt = hf * 3 + jj;
        short8 bv = *(const short8*)&smem[VT_OFF + (nt * 16 + cl) * 72 + ks * 32 + kblk];
        oacc[jj] = __builtin_amdgcn_mfma_f32_16x16x32_bf16(ap, bv, oacc[jj], 0, 0, 0);
      }
    }
    #pragma unroll
    for (int jj = 0; jj < 3; ++jj) {
      #pragma unroll
      for (int r = 0; r < 4; ++r) {
        int row = t4 * 16 + (g << 2) + r;
        if (row < NTOK)
          smem[K_OFF + row * 104 + (hf * 3 + jj) * 16 + cl] = f2bf(oacc[jj][r]);
      }
    }
    __syncthreads();

    // ---- proj partial: outacc += O @ proj_w_head^T ----
    #pragma unroll
    for (int ks = 0; ks < 3; ++ks) {
      short8 ao = *(const short8*)&smem[K_OFF + (t4 * 16 + cl) * 104 + ks * 32 + kblk];
      #pragma unroll
      for (int jj = 0; jj < 3; ++jj) {
        int nt = hf * 3 + jj;
        short8 bp = *(const short8*)&pw_swz[(size_t)((h * 6 + nt) * 3 + ks) * 512 + lane * 8];
        outacc[jj] = __builtin_amdgcn_mfma_f32_16x16x32_bf16(ao, bp, outacc[jj], 0, 0, 0);
      }
    }
  }

  // ---- epilogue ----
  #pragma unroll
  for (int jj = 0; jj < 3; ++jj) {
    float pb = proj_b[(hf * 3 + jj) * 16 + cl];
    #pragma unroll
    for (int r = 0; r < 4; ++r) {
      int n = t4 * 16 + (g << 2) + r;
      if (n < NTOK)
        out[((size_t)b * NTOK + n) * 96 + (hf * 3 + jj) * 16 + cl] = outacc[jj][r] + pb;
    }
  }
}

extern "C" void kernel_launch(void* const* d_in, const int* in_sizes, int n_in,
                              void* d_out, int out_size, void* d_ws, size_t ws_size,
                              hipStream_t stream) {
  const float* x          = (const float*)d_in[0];
  const float* y          = (const float*)d_in[1];
  const float* z          = (const float*)d_in[2];
  const float* mask       = (const float*)d_in[3];
  const float* qkv_w      = (const float*)d_in[4];
  const float* qkv_b      = (const float*)d_in[5];
  const float* proj_w     = (const float*)d_in[6];
  const float* proj_b     = (const float*)d_in[7];
  const float* bias_table = (const float*)d_in[8];
  const int*   rel_index  = (const int*)d_in[9];

  int B  = in_sizes[0] / (NTOK * 96);
  int nW = in_sizes[3] / (NTOK * NTOK);

  unsigned short* w_swz  = (unsigned short*)d_ws;
  unsigned short* pw_swz = w_swz + 248832;
  float*          bias3  = (float*)(pw_swz + 27648);

  prep_kernel<<<1109, 256, 0, stream>>>(qkv_w, proj_w, bias_table, rel_index,
                                        w_swz, pw_swz, bias3);
  wattn_kernel<<<B, 512, 0, stream>>>(x, y, z, mask, qkv_b, proj_b,
                                      w_swz, pw_swz, bias3, (float*)d_out, nW);
}